// Round 1
// baseline (2619.092 us; speedup 1.0000x reference)
//
#include <hip/hip_runtime.h>

// Problem constants (fixed by the reference setup_inputs()).
#define N_NODES 100000
#define N_EDGES 1600000
#define IN_CH   128
#define HID_CH  64
#define OUT_CH  40

// ---------------------------------------------------------------------------
// deg / dinv
// ---------------------------------------------------------------------------
__global__ void k_init_deg(float* __restrict__ deg) {
    int i = blockIdx.x * blockDim.x + threadIdx.x;
    if (i < N_NODES) deg[i] = 1.0f;  // self-loop contributes 1
}

__global__ void k_count_deg(const int* __restrict__ ei, float* __restrict__ deg) {
    int e = blockIdx.x * blockDim.x + threadIdx.x;
    if (e < N_EDGES) atomicAdd(&deg[ei[N_EDGES + e]], 1.0f);  // col = targets
}

__global__ void k_dinv(const float* __restrict__ deg, float* __restrict__ dinv) {
    int i = blockIdx.x * blockDim.x + threadIdx.x;
    if (i < N_NODES) dinv[i] = rsqrtf(deg[i]);  // deg >= 1 always
}

// ---------------------------------------------------------------------------
// GEMM1: h1[N,64] = x[N,128] @ W1[128,64].  16 rows/block, W1 in LDS.
// thread: r = tid>>4 (row in block), cg = tid&15 (4-col group)
// ---------------------------------------------------------------------------
__global__ void k_gemm1(const float* __restrict__ x, const float* __restrict__ W1,
                        float* __restrict__ h1) {
    __shared__ float Wl[IN_CH * HID_CH];  // 32 KB
    int tid = threadIdx.x;
    float4* Wl4 = (float4*)Wl;
    const float4* W4 = (const float4*)W1;
    for (int i = tid; i < IN_CH * HID_CH / 4; i += 256) Wl4[i] = W4[i];
    __syncthreads();

    int row = blockIdx.x * 16 + (tid >> 4);
    int cg  = tid & 15;
    if (row >= N_NODES) return;

    const float4* xr = (const float4*)(x + (long long)row * IN_CH);
    float4 acc = {0.f, 0.f, 0.f, 0.f};
#pragma unroll
    for (int k4 = 0; k4 < IN_CH / 4; ++k4) {
        float4 xv = xr[k4];
        float4 w0 = Wl4[(k4 * 4 + 0) * 16 + cg];
        float4 w1 = Wl4[(k4 * 4 + 1) * 16 + cg];
        float4 w2 = Wl4[(k4 * 4 + 2) * 16 + cg];
        float4 w3 = Wl4[(k4 * 4 + 3) * 16 + cg];
        acc.x += xv.x * w0.x + xv.y * w1.x + xv.z * w2.x + xv.w * w3.x;
        acc.y += xv.x * w0.y + xv.y * w1.y + xv.z * w2.y + xv.w * w3.y;
        acc.z += xv.x * w0.z + xv.y * w1.z + xv.z * w2.z + xv.w * w3.z;
        acc.w += xv.x * w0.w + xv.y * w1.w + xv.z * w2.w + xv.w * w3.w;
    }
    ((float4*)h1)[(long long)row * 16 + cg] = acc;
}

// ---------------------------------------------------------------------------
// self-loop init of a1: a1[i] = h1[i] * dinv[i]^2   (full write -> no memset)
// ---------------------------------------------------------------------------
__global__ void k_self1(const float* __restrict__ h1, const float* __restrict__ dinv,
                        float* __restrict__ a1) {
    int idx = blockIdx.x * blockDim.x + threadIdx.x;  // N*16
    if (idx >= N_NODES * 16) return;
    int i = idx >> 4;
    float d = dinv[i];
    float w = d * d;
    float4 v = ((const float4*)h1)[idx];
    float4 o = {v.x * w, v.y * w, v.z * w, v.w * w};
    ((float4*)a1)[idx] = o;
}

// ---------------------------------------------------------------------------
// edge aggregation layer 1: a1[dst] += dinv[s]*dinv[d] * h1[src]  (atomics)
// 16 threads per edge, float4 gather + 4 scalar atomics
// ---------------------------------------------------------------------------
__global__ void k_agg1(const int* __restrict__ ei, const float* __restrict__ h1,
                       const float* __restrict__ dinv, float* __restrict__ a1) {
    int idx = blockIdx.x * blockDim.x + threadIdx.x;  // E*16
    if (idx >= N_EDGES * 16) return;
    int e  = idx >> 4;
    int cg = idx & 15;
    int s = ei[e];
    int d = ei[N_EDGES + e];
    float w = dinv[s] * dinv[d];
    float4 v = ((const float4*)h1)[(long long)s * 16 + cg];
    float* ad = a1 + (long long)d * HID_CH + cg * 4;
    atomicAdd(ad + 0, v.x * w);
    atomicAdd(ad + 1, v.y * w);
    atomicAdd(ad + 2, v.z * w);
    atomicAdd(ad + 3, v.w * w);
}

// ---------------------------------------------------------------------------
// GEMM2: h2[N,40] = relu(a1 + b1) @ W2[64,40].  25 rows/block (250 threads).
// ---------------------------------------------------------------------------
__global__ void k_gemm2(const float* __restrict__ a1, const float* __restrict__ W2,
                        const float* __restrict__ b1, float* __restrict__ h2) {
    __shared__ float Wl[HID_CH * OUT_CH];  // 10 KB
    __shared__ float bl[HID_CH];
    int tid = threadIdx.x;
    for (int i = tid; i < HID_CH * OUT_CH / 4; i += 256)
        ((float4*)Wl)[i] = ((const float4*)W2)[i];
    if (tid < HID_CH) bl[tid] = b1[tid];
    __syncthreads();

    if (tid >= 250) return;
    int row = blockIdx.x * 25 + tid / 10;
    int cg  = tid % 10;
    if (row >= N_NODES) return;

    const float4* ar = (const float4*)(a1 + (long long)row * HID_CH);
    float4 acc = {0.f, 0.f, 0.f, 0.f};
#pragma unroll
    for (int k4 = 0; k4 < HID_CH / 4; ++k4) {
        float4 xv = ar[k4];
        xv.x = fmaxf(xv.x + bl[k4 * 4 + 0], 0.f);
        xv.y = fmaxf(xv.y + bl[k4 * 4 + 1], 0.f);
        xv.z = fmaxf(xv.z + bl[k4 * 4 + 2], 0.f);
        xv.w = fmaxf(xv.w + bl[k4 * 4 + 3], 0.f);
        float4 w0 = ((float4*)Wl)[(k4 * 4 + 0) * 10 + cg];
        float4 w1 = ((float4*)Wl)[(k4 * 4 + 1) * 10 + cg];
        float4 w2 = ((float4*)Wl)[(k4 * 4 + 2) * 10 + cg];
        float4 w3 = ((float4*)Wl)[(k4 * 4 + 3) * 10 + cg];
        acc.x += xv.x * w0.x + xv.y * w1.x + xv.z * w2.x + xv.w * w3.x;
        acc.y += xv.x * w0.y + xv.y * w1.y + xv.z * w2.y + xv.w * w3.y;
        acc.z += xv.x * w0.z + xv.y * w1.z + xv.z * w2.z + xv.w * w3.z;
        acc.w += xv.x * w0.w + xv.y * w1.w + xv.z * w2.w + xv.w * w3.w;
    }
    ((float4*)h2)[(long long)row * 10 + cg] = acc;
}

// ---------------------------------------------------------------------------
// self-loop init of out: out[i] = h2[i]*dinv[i]^2 + b2   (full write)
// ---------------------------------------------------------------------------
__global__ void k_self2(const float* __restrict__ h2, const float* __restrict__ dinv,
                        const float* __restrict__ b2, float* __restrict__ out) {
    int idx = blockIdx.x * blockDim.x + threadIdx.x;  // N*10
    if (idx >= N_NODES * 10) return;
    int i = idx / 10;
    int j = idx % 10;
    float d = dinv[i];
    float w = d * d;
    float4 v = ((const float4*)h2)[idx];
    float4 b = ((const float4*)b2)[j];
    float4 o = {v.x * w + b.x, v.y * w + b.y, v.z * w + b.z, v.w * w + b.w};
    ((float4*)out)[idx] = o;
}

// ---------------------------------------------------------------------------
// edge aggregation layer 2: out[dst] += dinv[s]*dinv[d] * h2[src]  (atomics)
// 10 threads per edge
// ---------------------------------------------------------------------------
__global__ void k_agg2(const int* __restrict__ ei, const float* __restrict__ h2,
                       const float* __restrict__ dinv, float* __restrict__ out) {
    int idx = blockIdx.x * blockDim.x + threadIdx.x;  // E*10
    if (idx >= N_EDGES * 10) return;
    int e  = idx / 10;
    int cg = idx % 10;
    int s = ei[e];
    int d = ei[N_EDGES + e];
    float w = dinv[s] * dinv[d];
    float4 v = ((const float4*)h2)[(long long)s * 10 + cg];
    float* od = out + (long long)d * OUT_CH + cg * 4;
    atomicAdd(od + 0, v.x * w);
    atomicAdd(od + 1, v.y * w);
    atomicAdd(od + 2, v.z * w);
    atomicAdd(od + 3, v.w * w);
}

// ---------------------------------------------------------------------------
// launch
// ---------------------------------------------------------------------------
extern "C" void kernel_launch(void* const* d_in, const int* in_sizes, int n_in,
                              void* d_out, int out_size, void* d_ws, size_t ws_size,
                              hipStream_t stream) {
    const float* x  = (const float*)d_in[0];
    const int*   ei = (const int*)d_in[1];
    const float* W1 = (const float*)d_in[2];
    const float* b1 = (const float*)d_in[3];
    const float* W2 = (const float*)d_in[4];
    const float* b2 = (const float*)d_in[5];
    float* out = (float*)d_out;

    // workspace layout (floats): deg[N] dinv[N] h1[N*64] a1[N*64] h2[N*40]
    // total = 100000*(1+1+64+64+40)*4B = 68 MB
    float* ws   = (float*)d_ws;
    float* deg  = ws;
    float* dinv = ws + N_NODES;
    float* h1   = ws + 2 * N_NODES;
    float* a1   = h1 + (long long)N_NODES * HID_CH;
    float* h2   = a1 + (long long)N_NODES * HID_CH;

    const int B = 256;

    // degree + dinv
    k_init_deg<<<(N_NODES + B - 1) / B, B, 0, stream>>>(deg);
    k_count_deg<<<(N_EDGES + B - 1) / B, B, 0, stream>>>(ei, deg);
    k_dinv<<<(N_NODES + B - 1) / B, B, 0, stream>>>(deg, dinv);

    // layer 1
    k_gemm1<<<(N_NODES + 15) / 16, B, 0, stream>>>(x, W1, h1);
    k_self1<<<(N_NODES * 16 + B - 1) / B, B, 0, stream>>>(h1, dinv, a1);
    k_agg1<<<(N_EDGES * 16 + B - 1) / B, B, 0, stream>>>(ei, h1, dinv, a1);

    // layer 2
    k_gemm2<<<(N_NODES + 24) / 25, B, 0, stream>>>(a1, W2, b1, h2);
    k_self2<<<(N_NODES * 10 + B - 1) / B, B, 0, stream>>>(h2, dinv, b2, out);
    k_agg2<<<(N_EDGES * 10 + B - 1) / B, B, 0, stream>>>(ei, h2, dinv, out);
}

// Round 2
// 512.877 us; speedup vs baseline: 5.1067x; 5.1067x over previous
//
#include <hip/hip_runtime.h>

// Problem constants (fixed by the reference setup_inputs()).
#define N_NODES 100000
#define N_EDGES 1600000
#define IN_CH   128
#define HID_CH  64
#define OUT_CH  40
#define NBLK_SCAN ((N_NODES + 255) / 256)   // 391

// ---------------------------------------------------------------------------
// CSR build: histogram -> scan -> scatter.  No float atomics anywhere.
// ---------------------------------------------------------------------------
__global__ void k_zero_cnt(int* __restrict__ cnt) {
    int i = blockIdx.x * blockDim.x + threadIdx.x;
    if (i < N_NODES) cnt[i] = 0;
}

__global__ void k_hist(const int* __restrict__ ei, int* __restrict__ cnt) {
    int e = blockIdx.x * blockDim.x + threadIdx.x;
    if (e < N_EDGES) atomicAdd(&cnt[ei[N_EDGES + e]], 1);  // col = targets
}

// per-block inclusive scan of cnt -> tmp_incl; block totals -> partial
__global__ void k_scan1(const int* __restrict__ cnt, int* __restrict__ tmp_incl,
                        int* __restrict__ partial) {
    __shared__ int s[256];
    int tid = threadIdx.x;
    int i = blockIdx.x * 256 + tid;
    s[tid] = (i < N_NODES) ? cnt[i] : 0;
    __syncthreads();
#pragma unroll
    for (int off = 1; off < 256; off <<= 1) {
        int t = (tid >= off) ? s[tid - off] : 0;
        __syncthreads();
        s[tid] += t;
        __syncthreads();
    }
    if (i < N_NODES) tmp_incl[i] = s[tid];
    if (tid == 255) partial[blockIdx.x] = s[255];
}

// single-block scan of the 391 partials (512 threads)
__global__ void k_scan2(int* __restrict__ partial) {
    __shared__ int s[512];
    int tid = threadIdx.x;
    s[tid] = (tid < NBLK_SCAN) ? partial[tid] : 0;
    __syncthreads();
#pragma unroll
    for (int off = 1; off < 512; off <<= 1) {
        int t = (tid >= off) ? s[tid - off] : 0;
        __syncthreads();
        s[tid] += t;
        __syncthreads();
    }
    if (tid < NBLK_SCAN) partial[tid] = s[tid];  // inclusive
}

// finalize: row_start[i+1] = incl(i); cursor[i] = excl(i); dinv = rsqrt(1+cnt)
__global__ void k_scan3(const int* __restrict__ cnt, const int* __restrict__ tmp_incl,
                        const int* __restrict__ partial, int* __restrict__ row_start,
                        int* __restrict__ cursor, float* __restrict__ dinv) {
    int i = blockIdx.x * 256 + threadIdx.x;
    if (i >= N_NODES) return;
    int b = blockIdx.x;
    int off = (b == 0) ? 0 : partial[b - 1];
    int incl = tmp_incl[i] + off;
    int c = cnt[i];
    row_start[i + 1] = incl;
    cursor[i] = incl - c;
    dinv[i] = rsqrtf(1.0f + (float)c);
    if (i == 0) row_start[0] = 0;
}

__global__ void k_scatter(const int* __restrict__ ei, int* __restrict__ cursor,
                          int* __restrict__ csr_src) {
    int e = blockIdx.x * blockDim.x + threadIdx.x;
    if (e >= N_EDGES) return;
    int s = ei[e];
    int d = ei[N_EDGES + e];
    int pos = atomicAdd(&cursor[d], 1);
    csr_src[pos] = s;
}

// ---------------------------------------------------------------------------
// GEMM1 (+dinv scale): h1s[N,64] = (x[N,128] @ W1[128,64]) * dinv[row]
// 16 rows/block, W1 in LDS.
// ---------------------------------------------------------------------------
__global__ void k_gemm1(const float* __restrict__ x, const float* __restrict__ W1,
                        const float* __restrict__ dinv, float* __restrict__ h1s) {
    __shared__ float Wl[IN_CH * HID_CH];  // 32 KB
    int tid = threadIdx.x;
    float4* Wl4 = (float4*)Wl;
    const float4* W4 = (const float4*)W1;
    for (int i = tid; i < IN_CH * HID_CH / 4; i += 256) Wl4[i] = W4[i];
    __syncthreads();

    int row = blockIdx.x * 16 + (tid >> 4);
    int cg  = tid & 15;
    if (row >= N_NODES) return;

    const float4* xr = (const float4*)(x + (long long)row * IN_CH);
    float4 acc = {0.f, 0.f, 0.f, 0.f};
#pragma unroll
    for (int k4 = 0; k4 < IN_CH / 4; ++k4) {
        float4 xv = xr[k4];
        float4 w0 = Wl4[(k4 * 4 + 0) * 16 + cg];
        float4 w1 = Wl4[(k4 * 4 + 1) * 16 + cg];
        float4 w2 = Wl4[(k4 * 4 + 2) * 16 + cg];
        float4 w3 = Wl4[(k4 * 4 + 3) * 16 + cg];
        acc.x += xv.x * w0.x + xv.y * w1.x + xv.z * w2.x + xv.w * w3.x;
        acc.y += xv.x * w0.y + xv.y * w1.y + xv.z * w2.y + xv.w * w3.y;
        acc.z += xv.x * w0.z + xv.y * w1.z + xv.z * w2.z + xv.w * w3.z;
        acc.w += xv.x * w0.w + xv.y * w1.w + xv.z * w2.w + xv.w * w3.w;
    }
    float dd = dinv[row];
    acc.x *= dd; acc.y *= dd; acc.z *= dd; acc.w *= dd;
    ((float4*)h1s)[(long long)row * 16 + cg] = acc;
}

// ---------------------------------------------------------------------------
// CSR aggregation layer 1: a1[d] = dinv[d] * (h1s[d] + sum_{s in N(d)} h1s[s])
// 16 threads per node (one float4 each), 16 nodes per 256-block.
// ---------------------------------------------------------------------------
__global__ void k_agg1(const int* __restrict__ row_start, const int* __restrict__ csr_src,
                       const float* __restrict__ h1s, const float* __restrict__ dinv,
                       float* __restrict__ a1) {
    int idx = blockIdx.x * blockDim.x + threadIdx.x;
    int node = idx >> 4;
    int cg = idx & 15;
    if (node >= N_NODES) return;
    int beg = row_start[node];
    int end = row_start[node + 1];
    float4 acc = ((const float4*)h1s)[(long long)node * 16 + cg];  // self-loop
    for (int e = beg; e < end; ++e) {
        int s = csr_src[e];
        float4 v = ((const float4*)h1s)[(long long)s * 16 + cg];
        acc.x += v.x; acc.y += v.y; acc.z += v.z; acc.w += v.w;
    }
    float dd = dinv[node];
    acc.x *= dd; acc.y *= dd; acc.z *= dd; acc.w *= dd;
    ((float4*)a1)[(long long)node * 16 + cg] = acc;
}

// ---------------------------------------------------------------------------
// GEMM2 (+bias/relu in, +dinv scale out): h2s = (relu(a1+b1) @ W2) * dinv
// 25 rows/block (250 threads active).
// ---------------------------------------------------------------------------
__global__ void k_gemm2(const float* __restrict__ a1, const float* __restrict__ W2,
                        const float* __restrict__ b1, const float* __restrict__ dinv,
                        float* __restrict__ h2s) {
    __shared__ float Wl[HID_CH * OUT_CH];  // 10 KB
    __shared__ float bl[HID_CH];
    int tid = threadIdx.x;
    for (int i = tid; i < HID_CH * OUT_CH / 4; i += 256)
        ((float4*)Wl)[i] = ((const float4*)W2)[i];
    if (tid < HID_CH) bl[tid] = b1[tid];
    __syncthreads();

    if (tid >= 250) return;
    int row = blockIdx.x * 25 + tid / 10;
    int cg  = tid % 10;
    if (row >= N_NODES) return;

    const float4* ar = (const float4*)(a1 + (long long)row * HID_CH);
    float4 acc = {0.f, 0.f, 0.f, 0.f};
#pragma unroll
    for (int k4 = 0; k4 < HID_CH / 4; ++k4) {
        float4 xv = ar[k4];
        xv.x = fmaxf(xv.x + bl[k4 * 4 + 0], 0.f);
        xv.y = fmaxf(xv.y + bl[k4 * 4 + 1], 0.f);
        xv.z = fmaxf(xv.z + bl[k4 * 4 + 2], 0.f);
        xv.w = fmaxf(xv.w + bl[k4 * 4 + 3], 0.f);
        float4 w0 = ((float4*)Wl)[(k4 * 4 + 0) * 10 + cg];
        float4 w1 = ((float4*)Wl)[(k4 * 4 + 1) * 10 + cg];
        float4 w2 = ((float4*)Wl)[(k4 * 4 + 2) * 10 + cg];
        float4 w3 = ((float4*)Wl)[(k4 * 4 + 3) * 10 + cg];
        acc.x += xv.x * w0.x + xv.y * w1.x + xv.z * w2.x + xv.w * w3.x;
        acc.y += xv.x * w0.y + xv.y * w1.y + xv.z * w2.y + xv.w * w3.y;
        acc.z += xv.x * w0.z + xv.y * w1.z + xv.z * w2.z + xv.w * w3.z;
        acc.w += xv.x * w0.w + xv.y * w1.w + xv.z * w2.w + xv.w * w3.w;
    }
    float dd = dinv[row];
    acc.x *= dd; acc.y *= dd; acc.z *= dd; acc.w *= dd;
    ((float4*)h2s)[(long long)row * 10 + cg] = acc;
}

// ---------------------------------------------------------------------------
// CSR aggregation layer 2 (+bias): out[d] = dinv[d]*(h2s[d]+sum h2s[s]) + b2
// 16 threads per node, cg<10 active (40 ch = 10 float4).
// ---------------------------------------------------------------------------
__global__ void k_agg2(const int* __restrict__ row_start, const int* __restrict__ csr_src,
                       const float* __restrict__ h2s, const float* __restrict__ dinv,
                       const float* __restrict__ b2, float* __restrict__ out) {
    int idx = blockIdx.x * blockDim.x + threadIdx.x;
    int node = idx >> 4;
    int cg = idx & 15;
    if (node >= N_NODES || cg >= 10) return;
    int beg = row_start[node];
    int end = row_start[node + 1];
    float4 acc = ((const float4*)h2s)[(long long)node * 10 + cg];  // self-loop
    for (int e = beg; e < end; ++e) {
        int s = csr_src[e];
        float4 v = ((const float4*)h2s)[(long long)s * 10 + cg];
        acc.x += v.x; acc.y += v.y; acc.z += v.z; acc.w += v.w;
    }
    float dd = dinv[node];
    float4 b = ((const float4*)b2)[cg];
    acc.x = acc.x * dd + b.x;
    acc.y = acc.y * dd + b.y;
    acc.z = acc.z * dd + b.z;
    acc.w = acc.w * dd + b.w;
    ((float4*)out)[(long long)node * 10 + cg] = acc;
}

// ---------------------------------------------------------------------------
// launch
// ---------------------------------------------------------------------------
extern "C" void kernel_launch(void* const* d_in, const int* in_sizes, int n_in,
                              void* d_out, int out_size, void* d_ws, size_t ws_size,
                              hipStream_t stream) {
    const float* x  = (const float*)d_in[0];
    const int*   ei = (const int*)d_in[1];
    const float* W1 = (const float*)d_in[2];
    const float* b1 = (const float*)d_in[3];
    const float* W2 = (const float*)d_in[4];
    const float* b2 = (const float*)d_in[5];
    float* out = (float*)d_out;

    // workspace layout (4B elems, all offsets multiple of 4 elems for float4):
    // cnt[N] tmp_incl[N] partial[512] row_start[N+4] cursor[N] csr_src[E]
    // dinv[N] h1s[N*64] a1[N*64] h2s[N*40]   -> ~75.6 MB
    int* wsi = (int*)d_ws;
    int* cnt       = wsi;                       // N
    int* tmp_incl  = cnt + N_NODES;             // N
    int* partial   = tmp_incl + N_NODES;        // 512
    int* row_start = partial + 512;             // N+4 (padded)
    int* cursor    = row_start + N_NODES + 4;   // N
    int* csr_src   = cursor + N_NODES;          // E
    float* dinv    = (float*)(csr_src + N_EDGES);        // N
    float* h1s     = dinv + N_NODES;                     // N*64
    float* a1      = h1s + (long long)N_NODES * HID_CH;  // N*64
    float* h2s     = a1 + (long long)N_NODES * HID_CH;   // N*40

    const int B = 256;
    const int gN  = (N_NODES + B - 1) / B;
    const int gE  = (N_EDGES + B - 1) / B;
    const int g16 = (N_NODES * 16 + B - 1) / B;

    // CSR build + dinv
    k_zero_cnt<<<gN, B, 0, stream>>>(cnt);
    k_hist<<<gE, B, 0, stream>>>(ei, cnt);
    k_scan1<<<NBLK_SCAN, 256, 0, stream>>>(cnt, tmp_incl, partial);
    k_scan2<<<1, 512, 0, stream>>>(partial);
    k_scan3<<<NBLK_SCAN, 256, 0, stream>>>(cnt, tmp_incl, partial, row_start, cursor, dinv);
    k_scatter<<<gE, B, 0, stream>>>(ei, cursor, csr_src);

    // layer 1
    k_gemm1<<<(N_NODES + 15) / 16, B, 0, stream>>>(x, W1, dinv, h1s);
    k_agg1<<<g16, B, 0, stream>>>(row_start, csr_src, h1s, dinv, a1);

    // layer 2
    k_gemm2<<<(N_NODES + 24) / 25, B, 0, stream>>>(a1, W2, b1, dinv, h2s);
    k_agg2<<<g16, B, 0, stream>>>(row_start, csr_src, h2s, dinv, b2, out);
}